// Round 29
// baseline (188.776 us; speedup 1.0000x reference)
//
#include <hip/hip_runtime.h>
#include <hip/hip_bf16.h>

typedef __bf16 bf16_t;
typedef __bf16 bf16x8 __attribute__((ext_vector_type(8)));
typedef float f32x4 __attribute__((ext_vector_type(4)));

constexpr int Bz = 8, Lseq = 1024, Dm = 512, Hh = 8, DKd = 64;
constexpr int MTOK = Bz * Lseq;   // 8192 tokens
constexpr int NREL = 201;
constexpr int PROW = 202;         // padded LDS row (bank stride 101%32=5, coprime)

// pos pre-scale: 0.125 (1/sqrt(dk)) * log2(e), folded so p = exp2(st*C + pos)
#define POS_C 0.18033688011112042f

__device__ inline float fexp2(float x) {
#if __has_builtin(__builtin_amdgcn_exp2f)
  return __builtin_amdgcn_exp2f(x);
#else
  return exp2f(x);
#endif
}
__device__ inline float b2f(unsigned short u) {
  return __builtin_bit_cast(float, (unsigned)u << 16);
}
__device__ inline unsigned pack2(float a, float b) {
  unsigned short ua = __builtin_bit_cast(unsigned short, (bf16_t)a);
  unsigned short ub = __builtin_bit_cast(unsigned short, (bf16_t)b);
  return (unsigned)ua | ((unsigned)ub << 16);
}

// ---------------- weights + rel cast (q/k/v cast now fused into proj) ---------
__global__ __launch_bounds__(256) void k_castw(
    const float* __restrict__ w0, const float* __restrict__ w1,
    const float* __restrict__ w2, const float* __restrict__ w3,
    const float* __restrict__ rel, bf16_t* __restrict__ d0,
    bf16_t* __restrict__ d1, bf16_t* __restrict__ d2, bf16_t* __restrict__ d3,
    bf16_t* __restrict__ drel) {
  const int x = blockIdx.x;
  if (x < 1024) {
    const int wsel = x >> 8;
    const float* s = wsel == 0 ? w0 : wsel == 1 ? w1 : wsel == 2 ? w2 : w3;
    bf16_t* d = wsel == 0 ? d0 : wsel == 1 ? d1 : wsel == 2 ? d2 : d3;
    const int i = ((x & 255) * 256 + threadIdx.x) * 4;
    float4 vv = *reinterpret_cast<const float4*>(s + i);
    d[i + 0] = (bf16_t)vv.x;
    d[i + 1] = (bf16_t)vv.y;
    d[i + 2] = (bf16_t)vv.z;
    d[i + 3] = (bf16_t)vv.w;
  } else {
    const int i = ((x - 1024) * 256 + threadIdx.x) * 4;
    if (i < NREL * DKd) {   // 12864 divisible by 4 -> exact
      float4 vv = *reinterpret_cast<const float4*>(rel + i);
      drel[i + 0] = (bf16_t)vv.x;
      drel[i + 1] = (bf16_t)vv.y;
      drel[i + 2] = (bf16_t)vv.z;
      drel[i + 3] = (bf16_t)vv.w;
    }
  }
}

// ---------------- ALL projections, fp32-A fused cast: one z=3 launch ----------
// 256x64 tile + 2-deep prefetch (the structure that made fp32-direct viable:
// 16 indep MFMA chains/half-step hide the doubled A-load bytes; cvt of buffer
// B overlaps buffer A's MFMAs — unlike r11/r16's naked 64x64 chain).
// A selected by block-uniform z (scalar select); W/out via offset arithmetic.
// z<2: head-major store; z==2: LDS-transpose coalesced store.
__global__ __launch_bounds__(256) void k_proj3f(const float* __restrict__ Aq,
                                                const float* __restrict__ Ak,
                                                const float* __restrict__ Av,
                                                const bf16_t* __restrict__ W,
                                                bf16_t* __restrict__ outb) {
  __shared__ bf16_t Vl[64][264];   // used only by z==2 path
  const int lane = threadIdx.x & 63, w = threadIdx.x >> 6;
  const int lr = lane & 15, lg = lane >> 4;
  const int z = blockIdx.z;
  const float* A = z == 0 ? Aq : z == 1 ? Ak : Av;
  W += (size_t)z * ((size_t)Dm * Dm);
  outb += (size_t)z * ((size_t)MTOK * Dm);
  // bijective chunked XCD swizzle (nwg=256, chunk=32)
  const int orig = blockIdx.x + blockIdx.y * 8;
  const int swz = ((orig & 7) << 5) | (orig >> 3);
  const int Rtile = (swz >> 3) * 256;            // 1024%256==0: no batch cross
  const int Rbase = Rtile + w * 64;              // wave-private 64 rows
  const int Cbase = (swz & 7) * 64;              // block-shared 64 cols

  f32x4 acc[4][4] = {};
  bf16x8 afA[4], wfA[4], afB[4], wfB[4];
  auto loadF = [&](bf16x8 (&af)[4], bf16x8 (&wf)[4], int k0) {
#pragma unroll
    for (int i = 0; i < 4; ++i) {
      const float* ap = A + (size_t)(Rbase + i * 16 + lr) * Dm + k0 + lg * 8;
      float4 x = *reinterpret_cast<const float4*>(ap);
      float4 y = *reinterpret_cast<const float4*>(ap + 4);
      bf16x8 r;
      r[0] = (bf16_t)x.x; r[1] = (bf16_t)x.y; r[2] = (bf16_t)x.z; r[3] = (bf16_t)x.w;
      r[4] = (bf16_t)y.x; r[5] = (bf16_t)y.y; r[6] = (bf16_t)y.z; r[7] = (bf16_t)y.w;
      af[i] = r;
    }
#pragma unroll
    for (int j = 0; j < 4; ++j)
      wf[j] = *reinterpret_cast<const bf16x8*>(W + (size_t)(Cbase + j * 16 + lr) * Dm + k0 + lg * 8);
  };
  auto domfma = [&](const bf16x8 (&af)[4], const bf16x8 (&wf)[4]) {
#pragma unroll
    for (int i = 0; i < 4; ++i)
#pragma unroll
      for (int j = 0; j < 4; ++j)
        acc[i][j] = __builtin_amdgcn_mfma_f32_16x16x32_bf16(af[i], wf[j], acc[i][j], 0, 0, 0);
  };
  loadF(afA, wfA, 0);
#pragma unroll
  for (int k0 = 0; k0 < Dm; k0 += 64) {
    loadF(afB, wfB, k0 + 32);
    domfma(afA, wfA);
    if (k0 + 64 < Dm) loadF(afA, wfA, k0 + 64);
    domfma(afB, wfB);
  }

  if (z < 2) {
    // Q/K: head-major store
#pragma unroll
    for (int i = 0; i < 4; ++i)
#pragma unroll
      for (int j = 0; j < 4; ++j)
#pragma unroll
        for (int r = 0; r < 4; ++r) {
          const int gr = Rbase + i * 16 + lg * 4 + r;  // token row
          const int gc = Cbase + j * 16 + lr;          // output col
          const int bb = gr >> 10, qq = gr & 1023, hh = gc >> 6, dd = gc & 63;
          outb[(((size_t)(bb * Hh + hh)) * Lseq + qq) * DKd + dd] = (bf16_t)acc[i][j][r];
        }
  } else {
    // V: stage tile transposed into LDS: Vl[dd_local][qq_local]
#pragma unroll
    for (int i = 0; i < 4; ++i)
#pragma unroll
      for (int j = 0; j < 4; ++j)
#pragma unroll
        for (int r = 0; r < 4; ++r) {
          const int grl = w * 64 + i * 16 + lg * 4 + r;  // qq local 0..255
          const int gcl = j * 16 + lr;                   // dd local 0..63
          Vl[gcl][grl] = (bf16_t)acc[i][j][r];
        }
    __syncthreads();
    // cooperative coalesced store: thread -> (dd = tid/4, 64-qq chunk = 128B)
    const int tid = threadIdx.x;
    const int dd = tid >> 2, qq0 = (tid & 3) * 64;
    const int bb = Rtile >> 10, qrow = Rtile & 1023, hh = swz & 7;
    bf16_t* dst = outb + (((size_t)(bb * Hh + hh)) * DKd + dd) * Lseq + qrow + qq0;
#pragma unroll
    for (int c = 0; c < 8; ++c)
      *reinterpret_cast<bf16x8*>(dst + c * 8) =
          *reinterpret_cast<const bf16x8*>(&Vl[dd][qq0 + c * 8]);
  }
}

// ---------------- fc GEMM: 256x64 tile + prefetch, bf16 out + resid -----------
__global__ __launch_bounds__(256) void k_fc(const bf16_t* __restrict__ A,
                                            const bf16_t* __restrict__ W,
                                            bf16_t* __restrict__ yb,
                                            const float* __restrict__ resid) {
  const int lane = threadIdx.x & 63, w = threadIdx.x >> 6;
  const int lr = lane & 15, lg = lane >> 4;
  // bijective chunked XCD swizzle (nwg=256, chunk=32)
  const int orig = blockIdx.x + blockIdx.y * 8;
  const int swz = ((orig & 7) << 5) | (orig >> 3);
  const int Rbase = (swz >> 3) * 256 + w * 64;
  const int Cbase = (swz & 7) * 64;

  f32x4 acc[4][4] = {};
  bf16x8 afA[4], wfA[4], afB[4], wfB[4];
  auto loadF = [&](bf16x8 (&af)[4], bf16x8 (&wf)[4], int k0) {
#pragma unroll
    for (int i = 0; i < 4; ++i)
      af[i] = *reinterpret_cast<const bf16x8*>(A + (size_t)(Rbase + i * 16 + lr) * Dm + k0 + lg * 8);
#pragma unroll
    for (int j = 0; j < 4; ++j)
      wf[j] = *reinterpret_cast<const bf16x8*>(W + (size_t)(Cbase + j * 16 + lr) * Dm + k0 + lg * 8);
  };
  auto domfma = [&](const bf16x8 (&af)[4], const bf16x8 (&wf)[4]) {
#pragma unroll
    for (int i = 0; i < 4; ++i)
#pragma unroll
      for (int j = 0; j < 4; ++j)
        acc[i][j] = __builtin_amdgcn_mfma_f32_16x16x32_bf16(af[i], wf[j], acc[i][j], 0, 0, 0);
  };
  loadF(afA, wfA, 0);
#pragma unroll
  for (int k0 = 0; k0 < Dm; k0 += 64) {
    loadF(afB, wfB, k0 + 32);
    domfma(afA, wfA);
    if (k0 + 64 < Dm) loadF(afA, wfA, k0 + 64);
    domfma(afB, wfB);
  }
#pragma unroll
  for (int i = 0; i < 4; ++i)
#pragma unroll
    for (int j = 0; j < 4; ++j)
#pragma unroll
      for (int r = 0; r < 4; ++r) {
        const int gr = Rbase + i * 16 + lg * 4 + r;
        const int gc = Cbase + j * 16 + lr;
        const size_t idx = (size_t)gr * Dm + gc;
        yb[idx] = (bf16_t)(acc[i][j][r] + resid[idx]);
      }
}

// ---------------- flash attention + fused in-block posdot (84us, stable) ------
__global__ __launch_bounds__(256, 4) void k_attn(const bf16_t* __restrict__ Qh,
                                                 const bf16_t* __restrict__ Kh,
                                                 const bf16_t* __restrict__ Vt,
                                                 const bf16_t* __restrict__ relb,
                                                 bf16_t* __restrict__ attnb) {
  __shared__ float smemf[6528];   // pos 12928B + Pl 10240B = 23168B; Ml 26112B

  const int tid = threadIdx.x;
  const int wv = tid >> 6, lane = tid & 63;
  const int lr = lane & 15, lg = lane >> 4;
  // bijective chunked XCD swizzle (nwg=2048, chunk=256)
  const int gid = ((blockIdx.x & 7) << 8) | (blockIdx.x >> 3);
  const int bh = gid >> 5;
  const int qb = (gid & 31) << 5;             // 32-row q tile

  unsigned short* pls = reinterpret_cast<unsigned short*>(smemf);     // [32][202]
  unsigned* Pw = reinterpret_cast<unsigned*>(smemf) + 3232 + wv * 640; // [2][16][20]

  const bf16_t* Qp = Qh + ((size_t)bh * Lseq + qb) * DKd;
  const bf16_t* Kp = Kh + (size_t)bh * Lseq * DKd;
  const bf16_t* Vp = Vt + (size_t)bh * DKd * Lseq;

  // Q fragments (dual-use: B-operand for swapped QK^T, A-operand for posdot)
  bf16x8 qf[2][2];
#pragma unroll
  for (int t = 0; t < 2; ++t)
#pragma unroll
    for (int h = 0; h < 2; ++h)
      qf[t][h] = *reinterpret_cast<const bf16x8*>(Qp + (size_t)(t * 16 + lr) * DKd + h * 32 + lg * 8);

  // ---- in-block posdot: pls[q][200-r] = POS_C * dot(Q[q], rel[r]) -----------
  for (int n = wv; n < 13; n += 4) {
    const int rr0 = n * 16 + lr;
    const int rclamp = rr0 > 200 ? 200 : rr0;
    bf16x8 rf0 = *reinterpret_cast<const bf16x8*>(relb + (size_t)rclamp * DKd + lg * 8);
    bf16x8 rf1 = *reinterpret_cast<const bf16x8*>(relb + (size_t)rclamp * DKd + 32 + lg * 8);
#pragma unroll
    for (int t = 0; t < 2; ++t) {
      f32x4 st = {};
      st = __builtin_amdgcn_mfma_f32_16x16x32_bf16(qf[t][0], rf0, st, 0, 0, 0);
      st = __builtin_amdgcn_mfma_f32_16x16x32_bf16(qf[t][1], rf1, st, 0, 0, 0);
      if (rr0 <= 200) {
#pragma unroll
        for (int r = 0; r < 4; ++r)
          pls[(t * 16 + lg * 4 + r) * PROW + (200 - rr0)] =
              __builtin_bit_cast(unsigned short, (bf16_t)(st[r] * POS_C));
      }
    }
  }
  __syncthreads();

  // per-lane pos row bases + band-edge constants (already scaled by POS_C)
  const unsigned short* prow[2] = {pls + (size_t)lr * PROW,
                                   pls + (size_t)(16 + lr) * PROW};
  float pe0[2], pe200[2];
#pragma unroll
  for (int t = 0; t < 2; ++t) {
    pe0[t] = b2f(prow[t][0]);       // k <= q-100 side
    pe200[t] = b2f(prow[t][200]);   // k >= q+100 side
  }

  f32x4 Oacc[2][4] = {};
  float psum[2] = {0.f, 0.f};
  const int ldelta = lg * 4 - lr;

  const int kbase = wv * 256;
#pragma unroll 2
  for (int k0 = kbase; k0 < kbase + 256; k0 += 32) {
    bf16x8 kf[2][2];
#pragma unroll
    for (int u = 0; u < 2; ++u)
#pragma unroll
      for (int h = 0; h < 2; ++h)
        kf[u][h] = *reinterpret_cast<const bf16x8*>(Kp + (size_t)(k0 + u * 16 + lr) * DKd + h * 32 + lg * 8);

    __builtin_amdgcn_s_setprio(1);
#pragma unroll
    for (int t = 0; t < 2; ++t) {
      const int Qt = qb + t * 16;
      f32x4 st[2];
#pragma unroll
      for (int u = 0; u < 2; ++u) {
        f32x4 a = {};
        a = __builtin_amdgcn_mfma_f32_16x16x32_bf16(kf[u][0], qf[t][0], a, 0, 0, 0);
        a = __builtin_amdgcn_mfma_f32_16x16x32_bf16(kf[u][1], qf[t][1], a, 0, 0, 0);
        st[u] = a;  // element: q = Qt+lr (col), k = k0+u*16+lg*4+r (row)
      }
      float p[2][4];
      if (k0 + 131 <= Qt) {            // whole step below band: pos = pls[q][0]
#pragma unroll
        for (int u = 0; u < 2; ++u)
#pragma unroll
          for (int r = 0; r < 4; ++r)
            p[u][r] = fexp2(fmaf(st[u][r], POS_C, pe0[t]));
      } else if (k0 >= Qt + 115) {     // whole step above band: pos = pls[q][200]
#pragma unroll
        for (int u = 0; u < 2; ++u)
#pragma unroll
          for (int r = 0; r < 4; ++r)
            p[u][r] = fexp2(fmaf(st[u][r], POS_C, pe200[t]));
      } else {                         // in-band: clamped gather from LDS
#pragma unroll
        for (int u = 0; u < 2; ++u) {
          const int jb = k0 + u * 16 + 100 - Qt + ldelta;
#pragma unroll
          for (int r = 0; r < 4; ++r) {
            int j = jb + r;
            j = j < 0 ? 0 : (j > 200 ? 200 : j);
            p[u][r] = fexp2(fmaf(st[u][r], POS_C, b2f(prow[t][j])));
          }
        }
      }
#pragma unroll
      for (int u = 0; u < 2; ++u)
#pragma unroll
        for (int r = 0; r < 4; ++r) psum[t] += p[u][r];
      // pack to bf16, wave-private LDS transpose (D-layout -> B-frag layout)
#pragma unroll
      for (int u = 0; u < 2; ++u) {
        uint2 pk;
        pk.x = pack2(p[u][0], p[u][1]);
        pk.y = pack2(p[u][2], p[u][3]);
        *reinterpret_cast<uint2*>(&Pw[t * 320 + lr * 20 + u * 8 + lg * 2]) = pk;
      }
    }
    // PV: A = Vt fragment, B = P fragment read back from LDS
    bf16x8 pb[2];
#pragma unroll
    for (int t = 0; t < 2; ++t)
      pb[t] = *reinterpret_cast<const bf16x8*>(&Pw[t * 320 + lr * 20 + lg * 4]);
#pragma unroll
    for (int f = 0; f < 4; ++f) {
      bf16x8 vf = *reinterpret_cast<const bf16x8*>(Vp + (size_t)(f * 16 + lr) * Lseq + k0 + lg * 8);
#pragma unroll
      for (int t = 0; t < 2; ++t)
        Oacc[t][f] = __builtin_amdgcn_mfma_f32_16x16x32_bf16(vf, pb[t], Oacc[t][f], 0, 0, 0);
    }
    __builtin_amdgcn_s_setprio(0);
  }

  // ---- merge the four k-quarters (no-max partials combine by pure addition) --
  __syncthreads();   // k-loops done; pos+Pl dead -> reuse smem as Ml[3][64][34]
  float* Ml = smemf;
  if (wv) {
    float* m = Ml + ((wv - 1) * 64 + lane) * 34;
#pragma unroll
    for (int t = 0; t < 2; ++t)
#pragma unroll
      for (int f = 0; f < 4; ++f)
#pragma unroll
        for (int r = 0; r < 4; ++r) m[t * 16 + f * 4 + r] = Oacc[t][f][r];
    m[32] = psum[0];
    m[33] = psum[1];
  }
  __syncthreads();
  if (!wv) {
#pragma unroll
    for (int w2 = 0; w2 < 3; ++w2) {
      const float* m = Ml + (w2 * 64 + lane) * 34;
#pragma unroll
      for (int t = 0; t < 2; ++t) {
#pragma unroll
        for (int f = 0; f < 4; ++f)
#pragma unroll
          for (int r = 0; r < 4; ++r) Oacc[t][f][r] += m[t * 16 + f * 4 + r];
        psum[t] += m[32 + t];
      }
    }
    const int gb = bh >> 3, hh = bh & 7;
#pragma unroll
    for (int t = 0; t < 2; ++t) {
      float s = psum[t];
      s += __shfl_xor(s, 16);
      s += __shfl_xor(s, 32);
      const float inv = 1.0f / s;
      const int qg = qb + t * 16 + lr;
#pragma unroll
      for (int f = 0; f < 4; ++f) {
        uint2 ov;
        ov.x = pack2(Oacc[t][f][0] * inv, Oacc[t][f][1] * inv);
        ov.y = pack2(Oacc[t][f][2] * inv, Oacc[t][f][3] * inv);
        *reinterpret_cast<uint2*>(attnb + ((size_t)(gb * Lseq + qg)) * Dm + hh * DKd + f * 16 + lg * 4) = ov;
      }
    }
  }
}

// ---------------- row LayerNorm over D=512, bf16 input ------------------------
__global__ __launch_bounds__(256) void k_ln(const bf16_t* __restrict__ y,
                                            const float* __restrict__ g,
                                            const float* __restrict__ be,
                                            float* __restrict__ out) {
  const int row = blockIdx.x * 4 + (threadIdx.x >> 6);
  const int lane = threadIdx.x & 63;
  bf16x8 rv = *reinterpret_cast<const bf16x8*>(y + (size_t)row * Dm + lane * 8);
  float vv[8];
#pragma unroll
  for (int j = 0; j < 8; ++j) vv[j] = (float)rv[j];
  float s = 0.f, s2 = 0.f;
#pragma unroll
  for (int j = 0; j < 8; ++j) { s += vv[j]; s2 += vv[j] * vv[j]; }
  for (int mk = 1; mk < 64; mk <<= 1) {
    s += __shfl_xor(s, mk, 64);
    s2 += __shfl_xor(s2, mk, 64);
  }
  const float mu = s * (1.0f / Dm);
  const float var = s2 * (1.0f / Dm) - mu * mu;
  const float inv = rsqrtf(var + 1e-6f);
  float* op = out + (size_t)row * Dm + lane * 8;
  const float* gp = g + lane * 8;
  const float* bp = be + lane * 8;
#pragma unroll
  for (int j = 0; j < 8; ++j) op[j] = (vv[j] - mu) * inv * gp[j] + bp[j];
}

// ------------------------------------------------------------------------------
extern "C" void kernel_launch(void* const* d_in, const int* in_sizes, int n_in,
                              void* d_out, int out_size, void* d_ws, size_t ws_size,
                              hipStream_t stream) {
  const float* q   = (const float*)d_in[0];
  const float* k   = (const float*)d_in[1];
  const float* v   = (const float*)d_in[2];
  const float* Wq  = (const float*)d_in[3];
  const float* Wk  = (const float*)d_in[4];
  const float* Wv  = (const float*)d_in[5];
  const float* Wfc = (const float*)d_in[6];
  const float* rel = (const float*)d_in[7];
  const float* gam = (const float*)d_in[8];
  const float* bet = (const float*)d_in[9];

  char* ws = (char*)d_ws;
  size_t off = 0;
  auto take = [&](size_t bytes) {
    char* p = ws + off;
    off += (bytes + 255) & ~(size_t)255;
    return p;
  };
  // NOTE: wqb/wkb/wvb contiguous and Qhp/Khp/Vtp contiguous — required by the
  // z=3 projection launch (offset arithmetic for W and out).
  bf16_t* wqb  = (bf16_t*)take((size_t)Dm * Dm * 2);
  bf16_t* wkb  = (bf16_t*)take((size_t)Dm * Dm * 2);
  bf16_t* wvb  = (bf16_t*)take((size_t)Dm * Dm * 2);
  bf16_t* wfcb = (bf16_t*)take((size_t)Dm * Dm * 2);
  bf16_t* relb = (bf16_t*)take((size_t)NREL * DKd * 2);
  bf16_t* Qhp  = (bf16_t*)take((size_t)MTOK * Dm * 2);
  bf16_t* Khp  = (bf16_t*)take((size_t)MTOK * Dm * 2);
  bf16_t* Vtp  = (bf16_t*)take((size_t)MTOK * Dm * 2);
  bf16_t* attnb= (bf16_t*)take((size_t)MTOK * Dm * 2);
  bf16_t* yb   = (bf16_t*)take((size_t)MTOK * Dm * 2);

  // 1) weights + rel cast only (q/k/v cast fused into proj)
  k_castw<<<dim3(1037), 256, 0, stream>>>(
      Wq, Wk, Wv, Wfc, rel, wqb, wkb, wvb, wfcb, relb);
  // 2) ALL projections, fp32-A fused cast (256x64 tile, z=3, prefetch)
  k_proj3f<<<dim3(8, 32, 3), 256, 0, stream>>>(q, k, v, wqb, Qhp);
  // 3) attention (posdot fused in-block; stable 84us)
  k_attn<<<dim3(2048), 256, 0, stream>>>(Qhp, Khp, Vtp, relb, attnb);
  // 4) output GEMM + residual (256x64 tile, bf16 yb)
  k_fc<<<dim3(8, 32), 256, 0, stream>>>(attnb, wfcb, yb, q);
  // 5) LayerNorm (bf16 input)
  k_ln<<<dim3(MTOK / 4), 256, 0, stream>>>(yb, gam, bet, (float*)d_out);
}

// Round 30
// 170.673 us; speedup vs baseline: 1.1061x; 1.1061x over previous
//
#include <hip/hip_runtime.h>
#include <hip/hip_bf16.h>

typedef __bf16 bf16_t;
typedef __bf16 bf16x8 __attribute__((ext_vector_type(8)));
typedef float f32x4 __attribute__((ext_vector_type(4)));

constexpr int Bz = 8, Lseq = 1024, Dm = 512, Hh = 8, DKd = 64;
constexpr int MTOK = Bz * Lseq;   // 8192 tokens
constexpr int NREL = 201;
constexpr int PROW = 202;         // padded LDS row (bank stride 101%32=5, coprime)

// pos pre-scale: 0.125 (1/sqrt(dk)) * log2(e), folded so p = exp2(st*C + pos)
#define POS_C 0.18033688011112042f

__device__ inline float fexp2(float x) {
#if __has_builtin(__builtin_amdgcn_exp2f)
  return __builtin_amdgcn_exp2f(x);
#else
  return exp2f(x);
#endif
}
__device__ inline float b2f(unsigned short u) {
  return __builtin_bit_cast(float, (unsigned)u << 16);
}
__device__ inline unsigned pack2(float a, float b) {
  unsigned short ua = __builtin_bit_cast(unsigned short, (bf16_t)a);
  unsigned short ub = __builtin_bit_cast(unsigned short, (bf16_t)b);
  return (unsigned)ua | ((unsigned)ub << 16);
}

// ---------------- ONE launch for ALL casts ------------------------------------
__global__ __launch_bounds__(256) void k_cast_all(
    const float* __restrict__ q, const float* __restrict__ k,
    const float* __restrict__ v, const float* __restrict__ w0,
    const float* __restrict__ w1, const float* __restrict__ w2,
    const float* __restrict__ w3, const float* __restrict__ rel,
    bf16_t* __restrict__ qb, bf16_t* __restrict__ kb, bf16_t* __restrict__ vb,
    bf16_t* __restrict__ d0, bf16_t* __restrict__ d1, bf16_t* __restrict__ d2,
    bf16_t* __restrict__ d3, bf16_t* __restrict__ drel) {
  const int y = blockIdx.y;
  if (y < 3) {
    const float* s = y == 0 ? q : y == 1 ? k : v;
    bf16_t* d = y == 0 ? qb : y == 1 ? kb : vb;
    const int i = (blockIdx.x * 256 + threadIdx.x) * 8;
    float4 a = *reinterpret_cast<const float4*>(s + i);
    float4 b = *reinterpret_cast<const float4*>(s + i + 4);
    bf16x8 r;
    r[0] = (bf16_t)a.x; r[1] = (bf16_t)a.y; r[2] = (bf16_t)a.z; r[3] = (bf16_t)a.w;
    r[4] = (bf16_t)b.x; r[5] = (bf16_t)b.y; r[6] = (bf16_t)b.z; r[7] = (bf16_t)b.w;
    *reinterpret_cast<bf16x8*>(d + i) = r;
  } else {
    const int x = blockIdx.x;
    if (x < 1024) {
      const int wsel = x >> 8;
      const float* s = wsel == 0 ? w0 : wsel == 1 ? w1 : wsel == 2 ? w2 : w3;
      bf16_t* d = wsel == 0 ? d0 : wsel == 1 ? d1 : wsel == 2 ? d2 : d3;
      const int i = ((x & 255) * 256 + threadIdx.x) * 4;
      float4 vv = *reinterpret_cast<const float4*>(s + i);
      d[i + 0] = (bf16_t)vv.x;
      d[i + 1] = (bf16_t)vv.y;
      d[i + 2] = (bf16_t)vv.z;
      d[i + 3] = (bf16_t)vv.w;
    } else if (x < 1037) {
      const int i = ((x - 1024) * 256 + threadIdx.x) * 4;
      if (i < NREL * DKd) {
        float4 vv = *reinterpret_cast<const float4*>(rel + i);
        drel[i + 0] = (bf16_t)vv.x;
        drel[i + 1] = (bf16_t)vv.y;
        drel[i + 2] = (bf16_t)vv.z;
        drel[i + 3] = (bf16_t)vv.w;
      }
    }
  }
}

// ---------------- ALL projections: one z=3 launch, 256x64 tile, prefetch ------
// z in {0,1,2} = Q,K,V via pure offset arithmetic (qb/kb/vb, wqb/wkb/wvb,
// Qhp/Khp/Vtp contiguous in ws). Identical main loop (ratio 2.0, 16 MFMA
// chains/wave); only the UNIFORM epilogue branches: z<2 head-major store,
// z==2 LDS-transpose coalesced store. 768 blocks = 3/CU machine fill.
__global__ __launch_bounds__(256) void k_proj3(const bf16_t* __restrict__ A,
                                               const bf16_t* __restrict__ W,
                                               bf16_t* __restrict__ outb) {
  __shared__ bf16_t Vl[64][264];   // used only by z==2 path
  const int lane = threadIdx.x & 63, w = threadIdx.x >> 6;
  const int lr = lane & 15, lg = lane >> 4;
  const int z = blockIdx.z;
  const size_t zo = (size_t)z * ((size_t)MTOK * Dm);
  A += zo;
  W += (size_t)z * ((size_t)Dm * Dm);
  outb += zo;
  // bijective chunked XCD swizzle (nwg=256, chunk=32)
  const int orig = blockIdx.x + blockIdx.y * 8;
  const int swz = ((orig & 7) << 5) | (orig >> 3);
  const int Rtile = (swz >> 3) * 256;            // 1024%256==0: no batch cross
  const int Rbase = Rtile + w * 64;              // wave-private 64 rows
  const int Cbase = (swz & 7) * 64;              // block-shared 64 cols

  f32x4 acc[4][4] = {};
  bf16x8 afA[4], wfA[4], afB[4], wfB[4];
  auto loadF = [&](bf16x8 (&af)[4], bf16x8 (&wf)[4], int k0) {
#pragma unroll
    for (int i = 0; i < 4; ++i)
      af[i] = *reinterpret_cast<const bf16x8*>(A + (size_t)(Rbase + i * 16 + lr) * Dm + k0 + lg * 8);
#pragma unroll
    for (int j = 0; j < 4; ++j)
      wf[j] = *reinterpret_cast<const bf16x8*>(W + (size_t)(Cbase + j * 16 + lr) * Dm + k0 + lg * 8);
  };
  auto domfma = [&](const bf16x8 (&af)[4], const bf16x8 (&wf)[4]) {
#pragma unroll
    for (int i = 0; i < 4; ++i)
#pragma unroll
      for (int j = 0; j < 4; ++j)
        acc[i][j] = __builtin_amdgcn_mfma_f32_16x16x32_bf16(af[i], wf[j], acc[i][j], 0, 0, 0);
  };
  loadF(afA, wfA, 0);
#pragma unroll
  for (int k0 = 0; k0 < Dm; k0 += 64) {
    loadF(afB, wfB, k0 + 32);
    domfma(afA, wfA);
    if (k0 + 64 < Dm) loadF(afA, wfA, k0 + 64);
    domfma(afB, wfB);
  }

  if (z < 2) {
    // Q/K: head-major store
#pragma unroll
    for (int i = 0; i < 4; ++i)
#pragma unroll
      for (int j = 0; j < 4; ++j)
#pragma unroll
        for (int r = 0; r < 4; ++r) {
          const int gr = Rbase + i * 16 + lg * 4 + r;  // token row
          const int gc = Cbase + j * 16 + lr;          // output col
          const int bb = gr >> 10, qq = gr & 1023, hh = gc >> 6, dd = gc & 63;
          outb[(((size_t)(bb * Hh + hh)) * Lseq + qq) * DKd + dd] = (bf16_t)acc[i][j][r];
        }
  } else {
    // V: stage tile transposed into LDS: Vl[dd_local][qq_local]
#pragma unroll
    for (int i = 0; i < 4; ++i)
#pragma unroll
      for (int j = 0; j < 4; ++j)
#pragma unroll
        for (int r = 0; r < 4; ++r) {
          const int grl = w * 64 + i * 16 + lg * 4 + r;  // qq local 0..255
          const int gcl = j * 16 + lr;                   // dd local 0..63
          Vl[gcl][grl] = (bf16_t)acc[i][j][r];
        }
    __syncthreads();
    // cooperative coalesced store: thread -> (dd = tid/4, 64-qq chunk = 128B)
    const int tid = threadIdx.x;
    const int dd = tid >> 2, qq0 = (tid & 3) * 64;
    const int bb = Rtile >> 10, qrow = Rtile & 1023, hh = swz & 7;
    bf16_t* dst = outb + (((size_t)(bb * Hh + hh)) * DKd + dd) * Lseq + qrow + qq0;
#pragma unroll
    for (int c = 0; c < 8; ++c)
      *reinterpret_cast<bf16x8*>(dst + c * 8) =
          *reinterpret_cast<const bf16x8*>(&Vl[dd][qq0 + c * 8]);
  }
}

// ---------------- fc GEMM: 256x64 tile + prefetch, bf16 out + resid -----------
__global__ __launch_bounds__(256) void k_fc(const bf16_t* __restrict__ A,
                                            const bf16_t* __restrict__ W,
                                            bf16_t* __restrict__ yb,
                                            const float* __restrict__ resid) {
  const int lane = threadIdx.x & 63, w = threadIdx.x >> 6;
  const int lr = lane & 15, lg = lane >> 4;
  // bijective chunked XCD swizzle (nwg=256, chunk=32)
  const int orig = blockIdx.x + blockIdx.y * 8;
  const int swz = ((orig & 7) << 5) | (orig >> 3);
  const int Rbase = (swz >> 3) * 256 + w * 64;
  const int Cbase = (swz & 7) * 64;

  f32x4 acc[4][4] = {};
  bf16x8 afA[4], wfA[4], afB[4], wfB[4];
  auto loadF = [&](bf16x8 (&af)[4], bf16x8 (&wf)[4], int k0) {
#pragma unroll
    for (int i = 0; i < 4; ++i)
      af[i] = *reinterpret_cast<const bf16x8*>(A + (size_t)(Rbase + i * 16 + lr) * Dm + k0 + lg * 8);
#pragma unroll
    for (int j = 0; j < 4; ++j)
      wf[j] = *reinterpret_cast<const bf16x8*>(W + (size_t)(Cbase + j * 16 + lr) * Dm + k0 + lg * 8);
  };
  auto domfma = [&](const bf16x8 (&af)[4], const bf16x8 (&wf)[4]) {
#pragma unroll
    for (int i = 0; i < 4; ++i)
#pragma unroll
      for (int j = 0; j < 4; ++j)
        acc[i][j] = __builtin_amdgcn_mfma_f32_16x16x32_bf16(af[i], wf[j], acc[i][j], 0, 0, 0);
  };
  loadF(afA, wfA, 0);
#pragma unroll
  for (int k0 = 0; k0 < Dm; k0 += 64) {
    loadF(afB, wfB, k0 + 32);
    domfma(afA, wfA);
    if (k0 + 64 < Dm) loadF(afA, wfA, k0 + 64);
    domfma(afB, wfB);
  }
#pragma unroll
  for (int i = 0; i < 4; ++i)
#pragma unroll
    for (int j = 0; j < 4; ++j)
#pragma unroll
      for (int r = 0; r < 4; ++r) {
        const int gr = Rbase + i * 16 + lg * 4 + r;
        const int gc = Cbase + j * 16 + lr;
        const size_t idx = (size_t)gr * Dm + gc;
        yb[idx] = (bf16_t)(acc[i][j][r] + resid[idx]);
      }
}

// ---------------- flash attention + fused in-block posdot (84us, stable) ------
__global__ __launch_bounds__(256, 4) void k_attn(const bf16_t* __restrict__ Qh,
                                                 const bf16_t* __restrict__ Kh,
                                                 const bf16_t* __restrict__ Vt,
                                                 const bf16_t* __restrict__ relb,
                                                 bf16_t* __restrict__ attnb) {
  __shared__ float smemf[6528];   // pos 12928B + Pl 10240B = 23168B; Ml 26112B

  const int tid = threadIdx.x;
  const int wv = tid >> 6, lane = tid & 63;
  const int lr = lane & 15, lg = lane >> 4;
  // bijective chunked XCD swizzle (nwg=2048, chunk=256)
  const int gid = ((blockIdx.x & 7) << 8) | (blockIdx.x >> 3);
  const int bh = gid >> 5;
  const int qb = (gid & 31) << 5;             // 32-row q tile

  unsigned short* pls = reinterpret_cast<unsigned short*>(smemf);     // [32][202]
  unsigned* Pw = reinterpret_cast<unsigned*>(smemf) + 3232 + wv * 640; // [2][16][20]

  const bf16_t* Qp = Qh + ((size_t)bh * Lseq + qb) * DKd;
  const bf16_t* Kp = Kh + (size_t)bh * Lseq * DKd;
  const bf16_t* Vp = Vt + (size_t)bh * DKd * Lseq;

  // Q fragments (dual-use: B-operand for swapped QK^T, A-operand for posdot)
  bf16x8 qf[2][2];
#pragma unroll
  for (int t = 0; t < 2; ++t)
#pragma unroll
    for (int h = 0; h < 2; ++h)
      qf[t][h] = *reinterpret_cast<const bf16x8*>(Qp + (size_t)(t * 16 + lr) * DKd + h * 32 + lg * 8);

  // ---- in-block posdot: pls[q][200-r] = POS_C * dot(Q[q], rel[r]) -----------
  for (int n = wv; n < 13; n += 4) {
    const int rr0 = n * 16 + lr;
    const int rclamp = rr0 > 200 ? 200 : rr0;
    bf16x8 rf0 = *reinterpret_cast<const bf16x8*>(relb + (size_t)rclamp * DKd + lg * 8);
    bf16x8 rf1 = *reinterpret_cast<const bf16x8*>(relb + (size_t)rclamp * DKd + 32 + lg * 8);
#pragma unroll
    for (int t = 0; t < 2; ++t) {
      f32x4 st = {};
      st = __builtin_amdgcn_mfma_f32_16x16x32_bf16(qf[t][0], rf0, st, 0, 0, 0);
      st = __builtin_amdgcn_mfma_f32_16x16x32_bf16(qf[t][1], rf1, st, 0, 0, 0);
      if (rr0 <= 200) {
#pragma unroll
        for (int r = 0; r < 4; ++r)
          pls[(t * 16 + lg * 4 + r) * PROW + (200 - rr0)] =
              __builtin_bit_cast(unsigned short, (bf16_t)(st[r] * POS_C));
      }
    }
  }
  __syncthreads();

  // per-lane pos row bases + band-edge constants (already scaled by POS_C)
  const unsigned short* prow[2] = {pls + (size_t)lr * PROW,
                                   pls + (size_t)(16 + lr) * PROW};
  float pe0[2], pe200[2];
#pragma unroll
  for (int t = 0; t < 2; ++t) {
    pe0[t] = b2f(prow[t][0]);       // k <= q-100 side
    pe200[t] = b2f(prow[t][200]);   // k >= q+100 side
  }

  f32x4 Oacc[2][4] = {};
  float psum[2] = {0.f, 0.f};
  const int ldelta = lg * 4 - lr;

  const int kbase = wv * 256;
#pragma unroll 2
  for (int k0 = kbase; k0 < kbase + 256; k0 += 32) {
    bf16x8 kf[2][2];
#pragma unroll
    for (int u = 0; u < 2; ++u)
#pragma unroll
      for (int h = 0; h < 2; ++h)
        kf[u][h] = *reinterpret_cast<const bf16x8*>(Kp + (size_t)(k0 + u * 16 + lr) * DKd + h * 32 + lg * 8);

    __builtin_amdgcn_s_setprio(1);
#pragma unroll
    for (int t = 0; t < 2; ++t) {
      const int Qt = qb + t * 16;
      f32x4 st[2];
#pragma unroll
      for (int u = 0; u < 2; ++u) {
        f32x4 a = {};
        a = __builtin_amdgcn_mfma_f32_16x16x32_bf16(kf[u][0], qf[t][0], a, 0, 0, 0);
        a = __builtin_amdgcn_mfma_f32_16x16x32_bf16(kf[u][1], qf[t][1], a, 0, 0, 0);
        st[u] = a;  // element: q = Qt+lr (col), k = k0+u*16+lg*4+r (row)
      }
      float p[2][4];
      if (k0 + 131 <= Qt) {            // whole step below band: pos = pls[q][0]
#pragma unroll
        for (int u = 0; u < 2; ++u)
#pragma unroll
          for (int r = 0; r < 4; ++r)
            p[u][r] = fexp2(fmaf(st[u][r], POS_C, pe0[t]));
      } else if (k0 >= Qt + 115) {     // whole step above band: pos = pls[q][200]
#pragma unroll
        for (int u = 0; u < 2; ++u)
#pragma unroll
          for (int r = 0; r < 4; ++r)
            p[u][r] = fexp2(fmaf(st[u][r], POS_C, pe200[t]));
      } else {                         // in-band: clamped gather from LDS
#pragma unroll
        for (int u = 0; u < 2; ++u) {
          const int jb = k0 + u * 16 + 100 - Qt + ldelta;
#pragma unroll
          for (int r = 0; r < 4; ++r) {
            int j = jb + r;
            j = j < 0 ? 0 : (j > 200 ? 200 : j);
            p[u][r] = fexp2(fmaf(st[u][r], POS_C, b2f(prow[t][j])));
          }
        }
      }
#pragma unroll
      for (int u = 0; u < 2; ++u)
#pragma unroll
        for (int r = 0; r < 4; ++r) psum[t] += p[u][r];
      // pack to bf16, wave-private LDS transpose (D-layout -> B-frag layout)
#pragma unroll
      for (int u = 0; u < 2; ++u) {
        uint2 pk;
        pk.x = pack2(p[u][0], p[u][1]);
        pk.y = pack2(p[u][2], p[u][3]);
        *reinterpret_cast<uint2*>(&Pw[t * 320 + lr * 20 + u * 8 + lg * 2]) = pk;
      }
    }
    // PV: A = Vt fragment, B = P fragment read back from LDS
    bf16x8 pb[2];
#pragma unroll
    for (int t = 0; t < 2; ++t)
      pb[t] = *reinterpret_cast<const bf16x8*>(&Pw[t * 320 + lr * 20 + lg * 4]);
#pragma unroll
    for (int f = 0; f < 4; ++f) {
      bf16x8 vf = *reinterpret_cast<const bf16x8*>(Vp + (size_t)(f * 16 + lr) * Lseq + k0 + lg * 8);
#pragma unroll
      for (int t = 0; t < 2; ++t)
        Oacc[t][f] = __builtin_amdgcn_mfma_f32_16x16x32_bf16(vf, pb[t], Oacc[t][f], 0, 0, 0);
    }
    __builtin_amdgcn_s_setprio(0);
  }

  // ---- merge the four k-quarters (no-max partials combine by pure addition) --
  __syncthreads();   // k-loops done; pos+Pl dead -> reuse smem as Ml[3][64][34]
  float* Ml = smemf;
  if (wv) {
    float* m = Ml + ((wv - 1) * 64 + lane) * 34;
#pragma unroll
    for (int t = 0; t < 2; ++t)
#pragma unroll
      for (int f = 0; f < 4; ++f)
#pragma unroll
        for (int r = 0; r < 4; ++r) m[t * 16 + f * 4 + r] = Oacc[t][f][r];
    m[32] = psum[0];
    m[33] = psum[1];
  }
  __syncthreads();
  if (!wv) {
#pragma unroll
    for (int w2 = 0; w2 < 3; ++w2) {
      const float* m = Ml + (w2 * 64 + lane) * 34;
#pragma unroll
      for (int t = 0; t < 2; ++t) {
#pragma unroll
        for (int f = 0; f < 4; ++f)
#pragma unroll
          for (int r = 0; r < 4; ++r) Oacc[t][f][r] += m[t * 16 + f * 4 + r];
        psum[t] += m[32 + t];
      }
    }
    const int gb = bh >> 3, hh = bh & 7;
#pragma unroll
    for (int t = 0; t < 2; ++t) {
      float s = psum[t];
      s += __shfl_xor(s, 16);
      s += __shfl_xor(s, 32);
      const float inv = 1.0f / s;
      const int qg = qb + t * 16 + lr;
#pragma unroll
      for (int f = 0; f < 4; ++f) {
        uint2 ov;
        ov.x = pack2(Oacc[t][f][0] * inv, Oacc[t][f][1] * inv);
        ov.y = pack2(Oacc[t][f][2] * inv, Oacc[t][f][3] * inv);
        *reinterpret_cast<uint2*>(attnb + ((size_t)(gb * Lseq + qg)) * Dm + hh * DKd + f * 16 + lg * 4) = ov;
      }
    }
  }
}

// ---------------- row LayerNorm over D=512, bf16 input ------------------------
__global__ __launch_bounds__(256) void k_ln(const bf16_t* __restrict__ y,
                                            const float* __restrict__ g,
                                            const float* __restrict__ be,
                                            float* __restrict__ out) {
  const int row = blockIdx.x * 4 + (threadIdx.x >> 6);
  const int lane = threadIdx.x & 63;
  bf16x8 rv = *reinterpret_cast<const bf16x8*>(y + (size_t)row * Dm + lane * 8);
  float vv[8];
#pragma unroll
  for (int j = 0; j < 8; ++j) vv[j] = (float)rv[j];
  float s = 0.f, s2 = 0.f;
#pragma unroll
  for (int j = 0; j < 8; ++j) { s += vv[j]; s2 += vv[j] * vv[j]; }
  for (int mk = 1; mk < 64; mk <<= 1) {
    s += __shfl_xor(s, mk, 64);
    s2 += __shfl_xor(s2, mk, 64);
  }
  const float mu = s * (1.0f / Dm);
  const float var = s2 * (1.0f / Dm) - mu * mu;
  const float inv = rsqrtf(var + 1e-6f);
  float* op = out + (size_t)row * Dm + lane * 8;
  const float* gp = g + lane * 8;
  const float* bp = be + lane * 8;
#pragma unroll
  for (int j = 0; j < 8; ++j) op[j] = (vv[j] - mu) * inv * gp[j] + bp[j];
}

// ------------------------------------------------------------------------------
extern "C" void kernel_launch(void* const* d_in, const int* in_sizes, int n_in,
                              void* d_out, int out_size, void* d_ws, size_t ws_size,
                              hipStream_t stream) {
  const float* q   = (const float*)d_in[0];
  const float* k   = (const float*)d_in[1];
  const float* v   = (const float*)d_in[2];
  const float* Wq  = (const float*)d_in[3];
  const float* Wk  = (const float*)d_in[4];
  const float* Wv  = (const float*)d_in[5];
  const float* Wfc = (const float*)d_in[6];
  const float* rel = (const float*)d_in[7];
  const float* gam = (const float*)d_in[8];
  const float* bet = (const float*)d_in[9];

  char* ws = (char*)d_ws;
  size_t off = 0;
  auto take = [&](size_t bytes) {
    char* p = ws + off;
    off += (bytes + 255) & ~(size_t)255;
    return p;
  };
  // NOTE: wqb/wkb/wvb contiguous, qb/kb/vb contiguous, Qhp/Khp/Vtp contiguous —
  // required by the z=3 projection launch (pure offset arithmetic).
  bf16_t* wqb  = (bf16_t*)take((size_t)Dm * Dm * 2);
  bf16_t* wkb  = (bf16_t*)take((size_t)Dm * Dm * 2);
  bf16_t* wvb  = (bf16_t*)take((size_t)Dm * Dm * 2);
  bf16_t* wfcb = (bf16_t*)take((size_t)Dm * Dm * 2);
  bf16_t* relb = (bf16_t*)take((size_t)NREL * DKd * 2);
  bf16_t* qb   = (bf16_t*)take((size_t)MTOK * Dm * 2);
  bf16_t* kb   = (bf16_t*)take((size_t)MTOK * Dm * 2);
  bf16_t* vb   = (bf16_t*)take((size_t)MTOK * Dm * 2);
  bf16_t* Qhp  = (bf16_t*)take((size_t)MTOK * Dm * 2);
  bf16_t* Khp  = (bf16_t*)take((size_t)MTOK * Dm * 2);
  bf16_t* Vtp  = (bf16_t*)take((size_t)MTOK * Dm * 2);
  bf16_t* attnb= (bf16_t*)take((size_t)MTOK * Dm * 2);
  bf16_t* yb   = (bf16_t*)take((size_t)MTOK * Dm * 2);

  // 1) ALL casts (q/k/v + 4 weights + rel) in one launch
  k_cast_all<<<dim3(2048, 4), 256, 0, stream>>>(
      q, k, v, Wq, Wk, Wv, Wfc, rel, qb, kb, vb, wqb, wkb, wvb, wfcb, relb);
  // 2) ALL projections (Q,K,V) in one z=3 launch (256x64 tile, prefetch)
  k_proj3<<<dim3(8, 32, 3), 256, 0, stream>>>(qb, wqb, Qhp);
  // 3) attention (posdot fused in-block; stable 84us)
  k_attn<<<dim3(2048), 256, 0, stream>>>(Qhp, Khp, Vtp, relb, attnb);
  // 4) output GEMM + residual (256x64 tile, bf16 yb)
  k_fc<<<dim3(8, 32), 256, 0, stream>>>(attnb, wfcb, yb, q);
  // 5) LayerNorm (bf16 input)
  k_ln<<<dim3(MTOK / 4), 256, 0, stream>>>(yb, gam, bet, (float*)d_out);
}